// Round 5
// baseline (221.974 us; speedup 1.0000x reference)
//
#include <hip/hip_runtime.h>
#include <hip/hip_bf16.h>

// CompanyOperationEvaluation R5: 2-launch pipeline.
//  K1 prep: LDS-tiled weight transposes fp32->bf16 (N x K), 305 blocks.
//  K2 mega: 512 blocks x 32 rows — gather+cross, cf chain, W0, W1, W2+softmax
//           entirely in LDS (no intermediate global tensors).
// LDS plan (72.7 KB -> 2 blocks/CU, 8 waves/CU):
//   X[16640]      : feat(32x264)@0 / buf0(32x136)@8448 / buf1(32x136)@0 /
//                   x0(32x520)@0        (aliased by liveness)
//   high_sh[8448] : [cf2 | e] (32x264), later x1 (32x264)
//   b_sh[9216]    : 128-row x 72 B-staging chunk (all GEMMs)
//   w2_sh[2048]   : W2^T
// All strides (264/136/520/72) are ≡4 mod 32 words -> ≤2-way bank alias (free).

typedef __bf16 bf16x8 __attribute__((ext_vector_type(8)));
typedef float floatx4 __attribute__((ext_vector_type(4)));

__device__ __forceinline__ unsigned short f2bf(float x) {
  unsigned int u = __builtin_bit_cast(unsigned int, x);
  u = (u + 0x7FFFu + ((u >> 16) & 1u)) >> 16;
  return (unsigned short)u;
}

// ---------------------------------------------------------------------------
// K1 prep: weight transposes only. blocks 0..303 = 32x32 tiles, block 304 = W2.
// ---------------------------------------------------------------------------
__global__ __launch_bounds__(256) void prep_kernel(
    const float* __restrict__ Wf, const float* __restrict__ Wu,
    const float* __restrict__ W0, const float* __restrict__ W1,
    const float* __restrict__ W2,
    unsigned short* __restrict__ wfT, unsigned short* __restrict__ wuT,
    unsigned short* __restrict__ w0T, unsigned short* __restrict__ w1T,
    unsigned short* __restrict__ w2T) {
  __shared__ unsigned short tile[32][34];
  const int bid = blockIdx.x, tid = threadIdx.x;
  if (bid < 304) {
    int t = bid;
    const float* src; unsigned short* dst; int N, K, kt, nt;
    if (t < 32)       { src = Wf; dst = wfT; N = 128; K = 256; kt = t >> 2;       nt = t & 3; }
    else if (t < 48)  { t -= 32;  src = Wu; dst = wuT; N = 128; K = 128; kt = t >> 2; nt = t & 3; }
    else if (t < 176) { t -= 48;  src = W0; dst = w0T; N = 512; K = 256; kt = t >> 4; nt = t & 15; }
    else              { t -= 176; src = W1; dst = w1T; N = 256; K = 512; kt = t >> 3; nt = t & 7; }
    {
      int r = tid >> 3, cg = (tid & 7) * 4;
      float4 v = *(const float4*)(src + (size_t)(kt * 32 + r) * N + nt * 32 + cg);
      tile[r][cg + 0] = f2bf(v.x); tile[r][cg + 1] = f2bf(v.y);
      tile[r][cg + 2] = f2bf(v.z); tile[r][cg + 3] = f2bf(v.w);
    }
    __syncthreads();
    {
      int rp = tid >> 3, cg = (tid & 7) * 4;
      uint2 o;
      o.x = (unsigned)tile[cg + 0][rp] | ((unsigned)tile[cg + 1][rp] << 16);
      o.y = (unsigned)tile[cg + 2][rp] | ((unsigned)tile[cg + 3][rp] << 16);
      *(uint2*)(dst + (size_t)(nt * 32 + rp) * K + kt * 32 + cg) = o;
    }
  } else {
    // W2 256x8 -> 8x256
#pragma unroll
    for (int i = 0; i < 8; ++i) {
      int g = tid * 8 + i, k = g >> 3, n = g & 7;
      w2T[n * 256 + k] = f2bf(W2[g]);
    }
  }
}

// ---------------------------------------------------------------------------
// Shared 32x128 GEMM step: A (32 rows, stride LDA, k-depth K) from LDS;
// B slab = 128 n-rows of BT (row stride LDB), staged per BK=64 chunk into
// b_sh (pad 72). Wave covers 32 rows x 32-col strip -> acc[2][2].
// ---------------------------------------------------------------------------
template <int K, int LDA, int LDB>
__device__ __forceinline__ void gemm_32x128(
    const unsigned short* A_sh, const unsigned short* __restrict__ BT,
    unsigned short* b_sh, floatx4 acc[2][2]) {
  const int tid = threadIdx.x, lane = tid & 63, wave = tid >> 6;
  const int m16 = lane & 15, quad = lane >> 4;
#pragma unroll
  for (int mi = 0; mi < 2; ++mi)
#pragma unroll
    for (int ni = 0; ni < 2; ++ni) acc[mi][ni] = (floatx4){0.f, 0.f, 0.f, 0.f};
  for (int k0 = 0; k0 < K; k0 += 64) {
    __syncthreads();  // prev b_sh reads done; producer LDS writes visible
#pragma unroll
    for (int i = 0; i < 4; ++i) {
      int chunk = i * 256 + tid;
      int row = chunk >> 3, seg = chunk & 7;
      *(uint4*)&b_sh[row * 72 + seg * 8] =
          *(const uint4*)(BT + (size_t)row * LDB + k0 + seg * 8);
    }
    __syncthreads();
#pragma unroll
    for (int kk = 0; kk < 64; kk += 32) {
      bf16x8 a[2], b[2];
#pragma unroll
      for (int mi = 0; mi < 2; ++mi)
        a[mi] = *(const bf16x8*)&A_sh[(mi * 16 + m16) * LDA + k0 + kk + quad * 8];
#pragma unroll
      for (int ni = 0; ni < 2; ++ni)
        b[ni] = *(const bf16x8*)&b_sh[(wave * 32 + ni * 16 + m16) * 72 + kk + quad * 8];
#pragma unroll
      for (int mi = 0; mi < 2; ++mi)
#pragma unroll
        for (int ni = 0; ni < 2; ++ni)
          acc[mi][ni] = __builtin_amdgcn_mfma_f32_16x16x32_bf16(a[mi], b[ni], acc[mi][ni], 0, 0, 0);
    }
  }
  __syncthreads();  // all b_sh / A_sh reads done before caller's LDS writes
}

// epilogue: bias+relu, write to LDS tile. m89 C/D layout: col=lane&15,
// row=quad*4+reg. col = colbase + wave*32 + ni*16 + m16 (also bias index).
__device__ __forceinline__ void epi(const floatx4 acc[2][2],
                                    const float* __restrict__ bias, int colbase,
                                    unsigned short* dst, int ldd) {
  const int lane = threadIdx.x & 63, wave = threadIdx.x >> 6;
  const int m16 = lane & 15, quad = lane >> 4;
#pragma unroll
  for (int mi = 0; mi < 2; ++mi)
#pragma unroll
    for (int ni = 0; ni < 2; ++ni) {
      int col = colbase + wave * 32 + ni * 16 + m16;
      float bv = bias[col];
#pragma unroll
      for (int r = 0; r < 4; ++r)
        dst[(mi * 16 + quad * 4 + r) * ldd + col] =
            f2bf(fmaxf(acc[mi][ni][r] + bv, 0.f));
    }
}

// ---------------------------------------------------------------------------
// K2 mega: full per-row pipeline, 512 blocks x 32 rows.
// ---------------------------------------------------------------------------
__global__ __launch_bounds__(256) void mega_kernel(
    const float* __restrict__ features, const int* __restrict__ ent_idx,
    const float* __restrict__ head_tab, const float* __restrict__ ent_tab,
    const float* __restrict__ w_cf, const float* __restrict__ w_fc,
    const float* __restrict__ w_ef, const float* __restrict__ w_fe,
    const float* __restrict__ b_c, const float* __restrict__ b_e,
    const unsigned short* __restrict__ wfT, const unsigned short* __restrict__ wuT,
    const unsigned short* __restrict__ w0T, const unsigned short* __restrict__ w1T,
    const unsigned short* __restrict__ w2T,
    const float* __restrict__ bf_, const float* __restrict__ bu,
    const float* __restrict__ bias0, const float* __restrict__ bias1,
    const float* __restrict__ bias2, const int* __restrict__ target,
    float* __restrict__ out) {
  __shared__ __align__(16) unsigned short X[16640];       // 33.3 KB
  __shared__ __align__(16) unsigned short high_sh[8448];  // 16.9 KB
  __shared__ __align__(16) unsigned short b_sh[9216];     // 18.4 KB
  __shared__ __align__(16) unsigned short w2_sh[2048];    //  4.0 KB
  unsigned short* feat_sh = X;          // stride 264, rows 0..32
  unsigned short* buf0 = X + 8448;      // stride 136
  unsigned short* buf1 = X;             // stride 136 (feat dead by then)
  unsigned short* x0_sh = X;            // stride 520 (buf0/buf1 dead by then)
  unsigned short* x1_sh = high_sh;      // stride 264 (high dead after W0)
  const int tid = threadIdx.x;
  const int r0 = blockIdx.x * 32;

  // stage W2^T (1 uint4/thread = exactly 2048 ushort)
  *(uint4*)&w2_sh[tid * 8] = *(const uint4*)(w2T + tid * 8);

  // stage features fp32->bf16 into feat_sh (2048 float4, 8/thread, coalesced)
#pragma unroll
  for (int i = 0; i < 8; ++i) {
    int idx4 = i * 256 + tid;
    int row = idx4 >> 6, c = (idx4 & 63) * 4;
    float4 v = *(const float4*)(features + (size_t)(r0 + row) * 256 + c);
    uint2 o;
    o.x = (unsigned)f2bf(v.x) | ((unsigned)f2bf(v.y) << 16);
    o.y = (unsigned)f2bf(v.z) | ((unsigned)f2bf(v.w) << 16);
    *(uint2*)&feat_sh[row * 264 + c] = o;
  }

  // gather + cross_compress x2 (fp32 regs) -> e into high_sh[:,128:256].
  // 2 passes x (16 rows x 16 lanes, 8 elems/lane); shfl over 16-lane groups.
  {
    const float bc = b_c[0], be = b_e[0];
#pragma unroll
    for (int p = 0; p < 2; ++p) {
      const int rl = p * 16 + (tid >> 4);
      const int c = (tid & 15) * 8;
      const int idx = ent_idx[r0 + rl];
      float h[8], e[8], wcf[8], wfc[8], wef[8], wfe[8];
      {
        float4 t0 = *(const float4*)(head_tab + (size_t)idx * 128 + c);
        float4 t1 = *(const float4*)(head_tab + (size_t)idx * 128 + c + 4);
        h[0]=t0.x; h[1]=t0.y; h[2]=t0.z; h[3]=t0.w;
        h[4]=t1.x; h[5]=t1.y; h[6]=t1.z; h[7]=t1.w;
        t0 = *(const float4*)(ent_tab + (size_t)idx * 128 + c);
        t1 = *(const float4*)(ent_tab + (size_t)idx * 128 + c + 4);
        e[0]=t0.x; e[1]=t0.y; e[2]=t0.z; e[3]=t0.w;
        e[4]=t1.x; e[5]=t1.y; e[6]=t1.z; e[7]=t1.w;
        t0 = *(const float4*)(w_cf + c); t1 = *(const float4*)(w_cf + c + 4);
        wcf[0]=t0.x; wcf[1]=t0.y; wcf[2]=t0.z; wcf[3]=t0.w;
        wcf[4]=t1.x; wcf[5]=t1.y; wcf[6]=t1.z; wcf[7]=t1.w;
        t0 = *(const float4*)(w_fc + c); t1 = *(const float4*)(w_fc + c + 4);
        wfc[0]=t0.x; wfc[1]=t0.y; wfc[2]=t0.z; wfc[3]=t0.w;
        wfc[4]=t1.x; wfc[5]=t1.y; wfc[6]=t1.z; wfc[7]=t1.w;
        t0 = *(const float4*)(w_ef + c); t1 = *(const float4*)(w_ef + c + 4);
        wef[0]=t0.x; wef[1]=t0.y; wef[2]=t0.z; wef[3]=t0.w;
        wef[4]=t1.x; wef[5]=t1.y; wef[6]=t1.z; wef[7]=t1.w;
        t0 = *(const float4*)(w_fe + c); t1 = *(const float4*)(w_fe + c + 4);
        wfe[0]=t0.x; wfe[1]=t0.y; wfe[2]=t0.z; wfe[3]=t0.w;
        wfe[4]=t1.x; wfe[5]=t1.y; wfe[6]=t1.z; wfe[7]=t1.w;
      }
#pragma unroll
      for (int it = 0; it < 2; ++it) {
        float d0 = 0, d1 = 0, d2 = 0, d3 = 0;
#pragma unroll
        for (int j = 0; j < 8; ++j) {
          d0 += e[j] * wcf[j]; d1 += h[j] * wfc[j];
          d2 += e[j] * wef[j]; d3 += h[j] * wfe[j];
        }
#pragma unroll
        for (int s = 1; s < 16; s <<= 1) {
          d0 += __shfl_xor(d0, s); d1 += __shfl_xor(d1, s);
          d2 += __shfl_xor(d2, s); d3 += __shfl_xor(d3, s);
        }
        float nh2[8], ne2[8];
#pragma unroll
        for (int j = 0; j < 8; ++j) {
          nh2[j] = h[j] * d0 + e[j] * d1 + bc;
          ne2[j] = h[j] * d2 + e[j] * d3 + be;
        }
#pragma unroll
        for (int j = 0; j < 8; ++j) { h[j] = nh2[j]; e[j] = ne2[j]; }
      }
      uint4 v;
      v.x = (unsigned)f2bf(e[0]) | ((unsigned)f2bf(e[1]) << 16);
      v.y = (unsigned)f2bf(e[2]) | ((unsigned)f2bf(e[3]) << 16);
      v.z = (unsigned)f2bf(e[4]) | ((unsigned)f2bf(e[5]) << 16);
      v.w = (unsigned)f2bf(e[6]) | ((unsigned)f2bf(e[7]) << 16);
      *(uint4*)&high_sh[rl * 264 + 128 + c] = v;
    }
  }

  floatx4 acc[2][2];
  // L1: cf0 = relu(feat @ Wf + bf) -> buf0
  gemm_32x128<256, 264, 256>(feat_sh, wfT, b_sh, acc);
  epi(acc, bf_, 0, buf0, 136);
  // L2: cf1 = relu(cf0 @ Wu + bu) -> buf1 (feat region, feat dead)
  gemm_32x128<128, 136, 128>(buf0, wuT, b_sh, acc);
  epi(acc, bu, 0, buf1, 136);
  // L3: cf2 = relu(cf1 @ Wu + bu) -> high_sh[:,0:128]
  gemm_32x128<128, 136, 128>(buf1, wuT, b_sh, acc);
  epi(acc, bu, 0, high_sh, 264);
  // W0: x0 = relu(high @ W0 + b0) -> x0_sh (X region), 4 N-slabs of 128
#pragma unroll
  for (int nq = 0; nq < 4; ++nq) {
    gemm_32x128<256, 264, 256>(high_sh, w0T + (size_t)nq * 128 * 256, b_sh, acc);
    epi(acc, bias0, nq * 128, x0_sh, 520);
  }
  // W1: x1 = relu(x0 @ W1 + b1) -> x1_sh (high region), 2 N-slabs of 128
#pragma unroll
  for (int nh = 0; nh < 2; ++nh) {
    gemm_32x128<512, 520, 512>(x0_sh, w1T + (size_t)nh * 128 * 512, b_sh, acc);
    epi(acc, bias1, nh * 128, x1_sh, 264);
  }
  __syncthreads();
  // W2 GEMV + softmax + target: 8 lanes/row, 32 elems/lane
  {
    int row = tid >> 3, q = tid & 7;
    float p[8];
#pragma unroll
    for (int n = 0; n < 8; ++n) p[n] = 0.f;
#pragma unroll
    for (int jb = 0; jb < 4; ++jb) {
      bf16x8 xv = *(const bf16x8*)&x1_sh[row * 264 + q * 32 + jb * 8];
#pragma unroll
      for (int n = 0; n < 8; ++n) {
        bf16x8 wv = *(const bf16x8*)&w2_sh[n * 256 + q * 32 + jb * 8];
#pragma unroll
        for (int j = 0; j < 8; ++j) p[n] += (float)xv[j] * (float)wv[j];
      }
    }
#pragma unroll
    for (int s = 1; s < 8; s <<= 1)
#pragma unroll
      for (int n = 0; n < 8; ++n) p[n] += __shfl_xor(p[n], s);
    if (q == 0) {
      float mx = -1e30f;
#pragma unroll
      for (int n = 0; n < 8; ++n) {
        p[n] = fmaxf(p[n] + bias2[n], 0.f);
        mx = fmaxf(mx, p[n]);
      }
      float sum = 0.f;
#pragma unroll
      for (int n = 0; n < 8; ++n) { p[n] = __expf(p[n] - mx); sum += p[n]; }
      const float inv = 1.f / sum;
      const int gr = r0 + row;
      float4 o0 = {p[0] * inv, p[1] * inv, p[2] * inv, p[3] * inv};
      float4 o1 = {p[4] * inv, p[5] * inv, p[6] * inv, p[7] * inv};
      *(float4*)(out + (size_t)gr * 8) = o0;
      *(float4*)(out + (size_t)gr * 8 + 4) = o1;
      out[16384 * 8 + gr] = (float)target[gr];
    }
  }
}

extern "C" void kernel_launch(void* const* d_in, const int* in_sizes, int n_in,
                              void* d_out, int out_size, void* d_ws, size_t ws_size,
                              hipStream_t stream) {
  const float* features = (const float*)d_in[0];
  const int* ent_idx    = (const int*)d_in[1];
  const int* target     = (const int*)d_in[2];
  const float* Wf  = (const float*)d_in[3];
  const float* bf_ = (const float*)d_in[4];
  const float* Wu  = (const float*)d_in[5];
  const float* bu  = (const float*)d_in[6];
  const float* w_cf = (const float*)d_in[7];
  const float* w_fc = (const float*)d_in[8];
  const float* w_ef = (const float*)d_in[9];
  const float* w_fe = (const float*)d_in[10];
  const float* b_c  = (const float*)d_in[11];
  const float* b_e  = (const float*)d_in[12];
  const float* head_tab = (const float*)d_in[13];
  const float* ent_tab  = (const float*)d_in[14];
  const float* W0 = (const float*)d_in[15];
  const float* b0 = (const float*)d_in[16];
  const float* W1 = (const float*)d_in[17];
  const float* b1 = (const float*)d_in[18];
  const float* W2 = (const float*)d_in[19];
  const float* b2 = (const float*)d_in[20];
  float* out = (float*)d_out;

  unsigned short* ws = (unsigned short*)d_ws;
  size_t off = 0;
  auto alloc = [&](size_t n) { unsigned short* p = ws + off; off += n; return p; };
  unsigned short* wfT = alloc(32768);
  unsigned short* wuT = alloc(16384);
  unsigned short* w0T = alloc(131072);
  unsigned short* w1T = alloc(131072);
  unsigned short* w2T = alloc(2048);
  (void)ws_size; (void)in_sizes; (void)n_in; (void)out_size;

  prep_kernel<<<305, 256, 0, stream>>>(Wf, Wu, W0, W1, W2,
                                       wfT, wuT, w0T, w1T, w2T);
  mega_kernel<<<512, 256, 0, stream>>>(features, ent_idx, head_tab, ent_tab,
      w_cf, w_fc, w_ef, w_fe, b_c, b_e, wfT, wuT, w0T, w1T, w2T,
      bf_, bu, b0, b1, b2, target, out);
}

// Round 6
// 192.367 us; speedup vs baseline: 1.1539x; 1.1539x over previous
//
#include <hip/hip_runtime.h>
#include <hip/hip_bf16.h>

// CompanyOperationEvaluation R6: 4-launch pipeline (R4 topology, tuned).
//  K1 prep_T: weight transposes only (305 blocks, ~2 us).
//  K2 cf_chain: 256 blocks x 64 rows; fused gather+cross (writes
//     high[:,128:256] direct from regs) + feat->cf0->cf1->cf2 with buf1
//     aliased over dead feat region. 69.6 KB LDS -> 2 blocks/CU.
//  K3 gemm128: x0 = relu(high @ W0 + b0), proven 128x128 tile, 512 blocks.
//  K4 w1_final: 256 blocks x 64 rows x full N=256; x1 aliased into b_sh;
//     50.1 KB LDS -> 3 blocks/CU; wave=64rx64c acc[4][4] (m97 ratio);
//     fused W2 GEMV + softmax + target.
// Lesson bank (R2/R5): never feed MFMA from global at low occupancy; never
// shrink the M-tile-per-barrier below ~8 MFMAs/wave/chunk.

typedef __bf16 bf16x8 __attribute__((ext_vector_type(8)));
typedef float floatx4 __attribute__((ext_vector_type(4)));

__device__ __forceinline__ unsigned short f2bf(float x) {
  unsigned int u = __builtin_bit_cast(unsigned int, x);
  u = (u + 0x7FFFu + ((u >> 16) & 1u)) >> 16;
  return (unsigned short)u;
}

// ---------------------------------------------------------------------------
// K1 prep_T: 32x32 transpose tiles fp32(KxN) -> bf16(NxK); block 304 = W2.
// ---------------------------------------------------------------------------
__global__ __launch_bounds__(256) void prep_kernel(
    const float* __restrict__ Wf, const float* __restrict__ Wu,
    const float* __restrict__ W0, const float* __restrict__ W1,
    const float* __restrict__ W2,
    unsigned short* __restrict__ wfT, unsigned short* __restrict__ wuT,
    unsigned short* __restrict__ w0T, unsigned short* __restrict__ w1T,
    unsigned short* __restrict__ w2T) {
  __shared__ unsigned short tile[32][34];
  const int bid = blockIdx.x, tid = threadIdx.x;
  if (bid < 304) {
    int t = bid;
    const float* src; unsigned short* dst; int N, K, kt, nt;
    if (t < 32)       { src = Wf; dst = wfT; N = 128; K = 256; kt = t >> 2;       nt = t & 3; }
    else if (t < 48)  { t -= 32;  src = Wu; dst = wuT; N = 128; K = 128; kt = t >> 2; nt = t & 3; }
    else if (t < 176) { t -= 48;  src = W0; dst = w0T; N = 512; K = 256; kt = t >> 4; nt = t & 15; }
    else              { t -= 176; src = W1; dst = w1T; N = 256; K = 512; kt = t >> 3; nt = t & 7; }
    {
      int r = tid >> 3, cg = (tid & 7) * 4;
      float4 v = *(const float4*)(src + (size_t)(kt * 32 + r) * N + nt * 32 + cg);
      tile[r][cg + 0] = f2bf(v.x); tile[r][cg + 1] = f2bf(v.y);
      tile[r][cg + 2] = f2bf(v.z); tile[r][cg + 3] = f2bf(v.w);
    }
    __syncthreads();
    {
      int rp = tid >> 3, cg = (tid & 7) * 4;
      uint2 o;
      o.x = (unsigned)tile[cg + 0][rp] | ((unsigned)tile[cg + 1][rp] << 16);
      o.y = (unsigned)tile[cg + 2][rp] | ((unsigned)tile[cg + 3][rp] << 16);
      *(uint2*)(dst + (size_t)(nt * 32 + rp) * K + kt * 32 + cg) = o;
    }
  } else {
#pragma unroll
    for (int i = 0; i < 8; ++i) {
      int g = tid * 8 + i, k = g >> 3, n = g & 7;
      w2T[n * 256 + k] = f2bf(W2[g]);
    }
  }
}

// ---------------------------------------------------------------------------
// 64x128 GEMM step: A (64 rows, stride LDA) in LDS; B slab = 128 n-rows of BT
// (stride LDB) staged per BK=64 chunk into b_sh (pad 72). Waves 2x2: each
// 32 rows x 64 cols, acc[2][4] (8 MFMAs / 6 ds_read_b128 per kk).
// ---------------------------------------------------------------------------
template <int K, int LDA, int LDB>
__device__ __forceinline__ void gemm_64x128(
    const unsigned short* A_sh, const unsigned short* __restrict__ BT,
    unsigned short* b_sh, floatx4 acc[2][4]) {
  const int tid = threadIdx.x, lane = tid & 63, wave = tid >> 6;
  const int wm = wave >> 1, wn = wave & 1;
  const int m16 = lane & 15, quad = lane >> 4;
#pragma unroll
  for (int mi = 0; mi < 2; ++mi)
#pragma unroll
    for (int ni = 0; ni < 4; ++ni) acc[mi][ni] = (floatx4){0.f, 0.f, 0.f, 0.f};
  for (int k0 = 0; k0 < K; k0 += 64) {
    __syncthreads();  // prev b_sh reads done; producer LDS writes visible
#pragma unroll
    for (int i = 0; i < 4; ++i) {
      int chunk = i * 256 + tid;
      int row = chunk >> 3, seg = chunk & 7;
      *(uint4*)&b_sh[row * 72 + seg * 8] =
          *(const uint4*)(BT + (size_t)row * LDB + k0 + seg * 8);
    }
    __syncthreads();
#pragma unroll
    for (int kk = 0; kk < 64; kk += 32) {
      bf16x8 a[2], b[4];
#pragma unroll
      for (int mi = 0; mi < 2; ++mi)
        a[mi] = *(const bf16x8*)&A_sh[(wm * 32 + mi * 16 + m16) * LDA + k0 + kk + quad * 8];
#pragma unroll
      for (int ni = 0; ni < 4; ++ni)
        b[ni] = *(const bf16x8*)&b_sh[(wn * 64 + ni * 16 + m16) * 72 + kk + quad * 8];
#pragma unroll
      for (int mi = 0; mi < 2; ++mi)
#pragma unroll
        for (int ni = 0; ni < 4; ++ni)
          acc[mi][ni] = __builtin_amdgcn_mfma_f32_16x16x32_bf16(a[mi], b[ni], acc[mi][ni], 0, 0, 0);
    }
  }
  __syncthreads();  // all reads done before caller's (possibly aliased) writes
}

// epilogue to LDS: bias+relu. m89 C/D layout: col=lane&15, row=quad*4+reg.
__device__ __forceinline__ void epi64(const floatx4 acc[2][4],
                                      const float* __restrict__ bias,
                                      unsigned short* dst, int ldd) {
  const int lane = threadIdx.x & 63, wave = threadIdx.x >> 6;
  const int wm = wave >> 1, wn = wave & 1;
  const int m16 = lane & 15, quad = lane >> 4;
#pragma unroll
  for (int mi = 0; mi < 2; ++mi)
#pragma unroll
    for (int ni = 0; ni < 4; ++ni) {
      int col = wn * 64 + ni * 16 + m16;
      float bv = bias[col];
#pragma unroll
      for (int r = 0; r < 4; ++r)
        dst[(wm * 32 + mi * 16 + quad * 4 + r) * ldd + col] =
            f2bf(fmaxf(acc[mi][ni][r] + bv, 0.f));
    }
}

// ---------------------------------------------------------------------------
// K2 cf_chain: 256 blocks x 64 rows. Fused gather+cross + 3-layer MLP.
// LDS: feat(64x264)=33.8K [aliased by buf1], buf0(64x136)=17.4K, b_sh 18.4K.
// ---------------------------------------------------------------------------
__global__ __launch_bounds__(256) void cf_chain_kernel(
    const float* __restrict__ features, const int* __restrict__ ent_idx,
    const float* __restrict__ head_tab, const float* __restrict__ ent_tab,
    const float* __restrict__ w_cf, const float* __restrict__ w_fc,
    const float* __restrict__ w_ef, const float* __restrict__ w_fe,
    const float* __restrict__ b_c, const float* __restrict__ b_e,
    const unsigned short* __restrict__ wfT, const unsigned short* __restrict__ wuT,
    const float* __restrict__ bf_, const float* __restrict__ bu,
    unsigned short* __restrict__ high) {
  __shared__ __align__(16) unsigned short feat_sh[64 * 264];  // 33.8 KB
  __shared__ __align__(16) unsigned short buf0[64 * 136];     // 17.4 KB
  __shared__ __align__(16) unsigned short b_sh[128 * 72];     // 18.4 KB
  unsigned short* buf1 = feat_sh;  // aliased: feat dead after L1
  const int tid = threadIdx.x;
  const int r0 = blockIdx.x * 64;

  // stage features fp32->bf16: 64 rows x 256 cols = 4096 float4, 16/thread
#pragma unroll
  for (int i = 0; i < 16; ++i) {
    int idx4 = i * 256 + tid;
    int row = idx4 >> 6, c = (idx4 & 63) * 4;
    float4 v = *(const float4*)(features + (size_t)(r0 + row) * 256 + c);
    uint2 o;
    o.x = (unsigned)f2bf(v.x) | ((unsigned)f2bf(v.y) << 16);
    o.y = (unsigned)f2bf(v.z) | ((unsigned)f2bf(v.w) << 16);
    *(uint2*)&feat_sh[row * 264 + c] = o;
  }

  // gather + cross_compress x2 -> e straight to global high[:,128:256].
  // 4 passes x (16 rows x 16 lanes, 8 elems/lane), shfl over 16-lane groups.
  {
    const float bc = b_c[0], be = b_e[0];
#pragma unroll
    for (int p = 0; p < 4; ++p) {
      const int rl = p * 16 + (tid >> 4);
      const int c = (tid & 15) * 8;
      const int idx = ent_idx[r0 + rl];
      float h[8], e[8], wcf[8], wfc[8], wef[8], wfe[8];
      {
        float4 t0 = *(const float4*)(head_tab + (size_t)idx * 128 + c);
        float4 t1 = *(const float4*)(head_tab + (size_t)idx * 128 + c + 4);
        h[0]=t0.x; h[1]=t0.y; h[2]=t0.z; h[3]=t0.w;
        h[4]=t1.x; h[5]=t1.y; h[6]=t1.z; h[7]=t1.w;
        t0 = *(const float4*)(ent_tab + (size_t)idx * 128 + c);
        t1 = *(const float4*)(ent_tab + (size_t)idx * 128 + c + 4);
        e[0]=t0.x; e[1]=t0.y; e[2]=t0.z; e[3]=t0.w;
        e[4]=t1.x; e[5]=t1.y; e[6]=t1.z; e[7]=t1.w;
        t0 = *(const float4*)(w_cf + c); t1 = *(const float4*)(w_cf + c + 4);
        wcf[0]=t0.x; wcf[1]=t0.y; wcf[2]=t0.z; wcf[3]=t0.w;
        wcf[4]=t1.x; wcf[5]=t1.y; wcf[6]=t1.z; wcf[7]=t1.w;
        t0 = *(const float4*)(w_fc + c); t1 = *(const float4*)(w_fc + c + 4);
        wfc[0]=t0.x; wfc[1]=t0.y; wfc[2]=t0.z; wfc[3]=t0.w;
        wfc[4]=t1.x; wfc[5]=t1.y; wfc[6]=t1.z; wfc[7]=t1.w;
        t0 = *(const float4*)(w_ef + c); t1 = *(const float4*)(w_ef + c + 4);
        wef[0]=t0.x; wef[1]=t0.y; wef[2]=t0.z; wef[3]=t0.w;
        wef[4]=t1.x; wef[5]=t1.y; wef[6]=t1.z; wef[7]=t1.w;
        t0 = *(const float4*)(w_fe + c); t1 = *(const float4*)(w_fe + c + 4);
        wfe[0]=t0.x; wfe[1]=t0.y; wfe[2]=t0.z; wfe[3]=t0.w;
        wfe[4]=t1.x; wfe[5]=t1.y; wfe[6]=t1.z; wfe[7]=t1.w;
      }
#pragma unroll
      for (int it = 0; it < 2; ++it) {
        float d0 = 0, d1 = 0, d2 = 0, d3 = 0;
#pragma unroll
        for (int j = 0; j < 8; ++j) {
          d0 += e[j] * wcf[j]; d1 += h[j] * wfc[j];
          d2 += e[j] * wef[j]; d3 += h[j] * wfe[j];
        }
#pragma unroll
        for (int s = 1; s < 16; s <<= 1) {
          d0 += __shfl_xor(d0, s); d1 += __shfl_xor(d1, s);
          d2 += __shfl_xor(d2, s); d3 += __shfl_xor(d3, s);
        }
        float nh2[8], ne2[8];
#pragma unroll
        for (int j = 0; j < 8; ++j) {
          nh2[j] = h[j] * d0 + e[j] * d1 + bc;
          ne2[j] = h[j] * d2 + e[j] * d3 + be;
        }
#pragma unroll
        for (int j = 0; j < 8; ++j) { h[j] = nh2[j]; e[j] = ne2[j]; }
      }
      uint4 v;
      v.x = (unsigned)f2bf(e[0]) | ((unsigned)f2bf(e[1]) << 16);
      v.y = (unsigned)f2bf(e[2]) | ((unsigned)f2bf(e[3]) << 16);
      v.z = (unsigned)f2bf(e[4]) | ((unsigned)f2bf(e[5]) << 16);
      v.w = (unsigned)f2bf(e[6]) | ((unsigned)f2bf(e[7]) << 16);
      *(uint4*)(high + (size_t)(r0 + rl) * 256 + 128 + c) = v;
    }
  }

  floatx4 acc[2][4];
  const int lane = tid & 63, wave = tid >> 6;
  const int wm = wave >> 1, wn = wave & 1;
  const int m16 = lane & 15, quad = lane >> 4;
  // L1: cf0 = relu(feat @ Wf + bf) -> buf0
  gemm_64x128<256, 264, 256>(feat_sh, wfT, b_sh, acc);
  epi64(acc, bf_, buf0, 136);
  // L2: cf1 = relu(cf0 @ Wu + bu) -> buf1 (aliases feat)
  gemm_64x128<128, 136, 128>(buf0, wuT, b_sh, acc);
  epi64(acc, bu, buf1, 136);
  // L3: cf2 = relu(cf1 @ Wu + bu) -> high[:,0:128] (global)
  gemm_64x128<128, 136, 128>(buf1, wuT, b_sh, acc);
#pragma unroll
  for (int mi = 0; mi < 2; ++mi)
#pragma unroll
    for (int ni = 0; ni < 4; ++ni) {
      int col = wn * 64 + ni * 16 + m16;
      float bv = bu[col];
#pragma unroll
      for (int r = 0; r < 4; ++r) {
        int row = r0 + wm * 32 + mi * 16 + quad * 4 + r;
        high[(size_t)row * 256 + col] = f2bf(fmaxf(acc[mi][ni][r] + bv, 0.f));
      }
    }
}

// ---------------------------------------------------------------------------
// K3 gemm128: proven 128x128 tile, BK=64, 4 waves 2x2 (64x64, acc[4][4]).
// ---------------------------------------------------------------------------
__global__ __launch_bounds__(256) void gemm128_kernel(
    const unsigned short* __restrict__ A, const unsigned short* __restrict__ BT,
    const float* __restrict__ bias, unsigned short* __restrict__ C,
    int K, int ldc) {
  __shared__ __align__(16) unsigned short a_sh[128 * 72];
  __shared__ __align__(16) unsigned short b_sh[128 * 72];
  const int tid = threadIdx.x;
  const int bn = blockIdx.x, bm = blockIdx.y;
  const int lane = tid & 63;
  const int wave = tid >> 6;
  const int wm = wave & 1, wn = wave >> 1;
  const int m16 = lane & 15, quad = lane >> 4;

  floatx4 acc[4][4];
#pragma unroll
  for (int i = 0; i < 4; ++i)
#pragma unroll
    for (int j = 0; j < 4; ++j) acc[i][j] = (floatx4){0.f, 0.f, 0.f, 0.f};

  for (int k0 = 0; k0 < K; k0 += 64) {
    __syncthreads();
#pragma unroll
    for (int i = 0; i < 4; ++i) {
      int chunk = i * 256 + tid;
      int row = chunk >> 3, seg = chunk & 7;
      *(uint4*)&a_sh[row * 72 + seg * 8] =
          *(const uint4*)(A + (size_t)(bm * 128 + row) * K + k0 + seg * 8);
      *(uint4*)&b_sh[row * 72 + seg * 8] =
          *(const uint4*)(BT + (size_t)(bn * 128 + row) * K + k0 + seg * 8);
    }
    __syncthreads();
#pragma unroll
    for (int kk = 0; kk < 64; kk += 32) {
      bf16x8 af[4], bfr[4];
#pragma unroll
      for (int mi = 0; mi < 4; ++mi)
        af[mi] = *(const bf16x8*)&a_sh[(wm * 64 + mi * 16 + m16) * 72 + kk + quad * 8];
#pragma unroll
      for (int ni = 0; ni < 4; ++ni)
        bfr[ni] = *(const bf16x8*)&b_sh[(wn * 64 + ni * 16 + m16) * 72 + kk + quad * 8];
#pragma unroll
      for (int mi = 0; mi < 4; ++mi)
#pragma unroll
        for (int ni = 0; ni < 4; ++ni)
          acc[mi][ni] = __builtin_amdgcn_mfma_f32_16x16x32_bf16(
              af[mi], bfr[ni], acc[mi][ni], 0, 0, 0);
    }
  }
#pragma unroll
  for (int mi = 0; mi < 4; ++mi) {
#pragma unroll
    for (int ni = 0; ni < 4; ++ni) {
      int col = bn * 128 + wn * 64 + ni * 16 + m16;
      float bv = bias[col];
#pragma unroll
      for (int r = 0; r < 4; ++r) {
        int row = bm * 128 + wm * 64 + mi * 16 + quad * 4 + r;
        C[(size_t)row * ldc + col] = f2bf(fmaxf(acc[mi][ni][r] + bv, 0.f));
      }
    }
  }
}

// ---------------------------------------------------------------------------
// K4 w1_final: 256 blocks x 64 rows x full N=256. LDS 50.1 KB -> 3 blocks/CU.
// Wave: 64 rows x cols wave*64, acc[4][4] (16 MFMAs / 8 reads per kk).
// x1 aliased into b_sh. Fused W2 GEMV + softmax + target.
// ---------------------------------------------------------------------------
__global__ __launch_bounds__(256) void gemm_w1_final_kernel(
    const unsigned short* __restrict__ x0, const unsigned short* __restrict__ w1T,
    const float* __restrict__ b1, const unsigned short* __restrict__ w2T,
    const float* __restrict__ b2, const int* __restrict__ target,
    float* __restrict__ out) {
  __shared__ __align__(16) unsigned short a_sh[64 * 72];    //  9.2 KB
  __shared__ __align__(16) unsigned short b_sh[256 * 72];   // 36.9 KB
  __shared__ __align__(16) unsigned short w2_sh[2048];      //  4.0 KB
  unsigned short* x1_sh = b_sh;  // x1 tile 64x264 = 33.8 KB <= b_sh
  const int tid = threadIdx.x;
  const int r0 = blockIdx.x * 64;
  *(uint4*)&w2_sh[tid * 8] = *(const uint4*)(w2T + tid * 8);
  const int lane = tid & 63, wave = tid >> 6;
  const int m16 = lane & 15, quad = lane >> 4;
  floatx4 acc[4][4];
#pragma unroll
  for (int mi = 0; mi < 4; ++mi)
#pragma unroll
    for (int ni = 0; ni < 4; ++ni) acc[mi][ni] = (floatx4){0.f, 0.f, 0.f, 0.f};

  for (int k0 = 0; k0 < 512; k0 += 64) {
    __syncthreads();
    // stage A chunk: 64 rows x 64 k (512 uint4, 2/thread)
#pragma unroll
    for (int i = 0; i < 2; ++i) {
      int chunk = i * 256 + tid;
      int row = chunk >> 3, seg = chunk & 7;
      *(uint4*)&a_sh[row * 72 + seg * 8] =
          *(const uint4*)(x0 + (size_t)(r0 + row) * 512 + k0 + seg * 8);
    }
    // stage B chunk: 256 n-rows x 64 k (2048 uint4, 8/thread)
#pragma unroll
    for (int i = 0; i < 8; ++i) {
      int chunk = i * 256 + tid;
      int row = chunk >> 3, seg = chunk & 7;
      *(uint4*)&b_sh[row * 72 + seg * 8] =
          *(const uint4*)(w1T + (size_t)row * 512 + k0 + seg * 8);
    }
    __syncthreads();
#pragma unroll
    for (int kk = 0; kk < 64; kk += 32) {
      bf16x8 a[4], b[4];
#pragma unroll
      for (int mi = 0; mi < 4; ++mi)
        a[mi] = *(const bf16x8*)&a_sh[(mi * 16 + m16) * 72 + kk + quad * 8];
#pragma unroll
      for (int ni = 0; ni < 4; ++ni)
        b[ni] = *(const bf16x8*)&b_sh[(wave * 64 + ni * 16 + m16) * 72 + kk + quad * 8];
#pragma unroll
      for (int mi = 0; mi < 4; ++mi)
#pragma unroll
        for (int ni = 0; ni < 4; ++ni)
          acc[mi][ni] = __builtin_amdgcn_mfma_f32_16x16x32_bf16(a[mi], b[ni], acc[mi][ni], 0, 0, 0);
    }
  }
  __syncthreads();  // all b_sh MFMA reads done before aliased x1 writes
#pragma unroll
  for (int mi = 0; mi < 4; ++mi)
#pragma unroll
    for (int ni = 0; ni < 4; ++ni) {
      int col = wave * 64 + ni * 16 + m16;
      float bv = b1[col];
#pragma unroll
      for (int r = 0; r < 4; ++r)
        x1_sh[(mi * 16 + quad * 4 + r) * 264 + col] = f2bf(fmaxf(acc[mi][ni][r] + bv, 0.f));
    }
  __syncthreads();
  // W2 GEMV + softmax: 4 lanes/row, 64 elems/lane
  {
    int row = tid >> 2, q = tid & 3;
    float p[8];
#pragma unroll
    for (int n = 0; n < 8; ++n) p[n] = 0.f;
#pragma unroll
    for (int jb = 0; jb < 8; ++jb) {
      bf16x8 xv = *(const bf16x8*)&x1_sh[row * 264 + q * 64 + jb * 8];
#pragma unroll
      for (int n = 0; n < 8; ++n) {
        bf16x8 wv = *(const bf16x8*)&w2_sh[n * 256 + q * 64 + jb * 8];
#pragma unroll
        for (int j = 0; j < 8; ++j) p[n] += (float)xv[j] * (float)wv[j];
      }
    }
#pragma unroll
    for (int s = 1; s < 4; s <<= 1)
#pragma unroll
      for (int n = 0; n < 8; ++n) p[n] += __shfl_xor(p[n], s);
    if (q == 0) {
      float mx = -1e30f;
#pragma unroll
      for (int n = 0; n < 8; ++n) {
        p[n] = fmaxf(p[n] + b2[n], 0.f);
        mx = fmaxf(mx, p[n]);
      }
      float sum = 0.f;
#pragma unroll
      for (int n = 0; n < 8; ++n) { p[n] = __expf(p[n] - mx); sum += p[n]; }
      const float inv = 1.f / sum;
      const int gr = r0 + row;
      float4 o0 = {p[0] * inv, p[1] * inv, p[2] * inv, p[3] * inv};
      float4 o1 = {p[4] * inv, p[5] * inv, p[6] * inv, p[7] * inv};
      *(float4*)(out + (size_t)gr * 8) = o0;
      *(float4*)(out + (size_t)gr * 8 + 4) = o1;
      out[16384 * 8 + gr] = (float)target[gr];
    }
  }
}

extern "C" void kernel_launch(void* const* d_in, const int* in_sizes, int n_in,
                              void* d_out, int out_size, void* d_ws, size_t ws_size,
                              hipStream_t stream) {
  const float* features = (const float*)d_in[0];
  const int* ent_idx    = (const int*)d_in[1];
  const int* target     = (const int*)d_in[2];
  const float* Wf  = (const float*)d_in[3];
  const float* bf_ = (const float*)d_in[4];
  const float* Wu  = (const float*)d_in[5];
  const float* bu  = (const float*)d_in[6];
  const float* w_cf = (const float*)d_in[7];
  const float* w_fc = (const float*)d_in[8];
  const float* w_ef = (const float*)d_in[9];
  const float* w_fe = (const float*)d_in[10];
  const float* b_c  = (const float*)d_in[11];
  const float* b_e  = (const float*)d_in[12];
  const float* head_tab = (const float*)d_in[13];
  const float* ent_tab  = (const float*)d_in[14];
  const float* W0 = (const float*)d_in[15];
  const float* b0 = (const float*)d_in[16];
  const float* W1 = (const float*)d_in[17];
  const float* b1 = (const float*)d_in[18];
  const float* W2 = (const float*)d_in[19];
  const float* b2 = (const float*)d_in[20];
  float* out = (float*)d_out;

  unsigned short* ws = (unsigned short*)d_ws;
  size_t off = 0;
  auto alloc = [&](size_t n) { unsigned short* p = ws + off; off += n; return p; };
  unsigned short* high = alloc(16384ull * 256);
  unsigned short* x0   = alloc(16384ull * 512);
  unsigned short* wfT  = alloc(32768);
  unsigned short* wuT  = alloc(16384);
  unsigned short* w0T  = alloc(131072);
  unsigned short* w1T  = alloc(131072);
  unsigned short* w2T  = alloc(2048);
  (void)ws_size; (void)in_sizes; (void)n_in; (void)out_size;

  // K1: weight transposes
  prep_kernel<<<305, 256, 0, stream>>>(Wf, Wu, W0, W1, W2,
                                       wfT, wuT, w0T, w1T, w2T);
  // K2: gather+cross + cf chain -> full high
  cf_chain_kernel<<<256, 256, 0, stream>>>(features, ent_idx, head_tab,
      ent_tab, w_cf, w_fc, w_ef, w_fe, b_c, b_e, wfT, wuT, bf_, bu, high);
  // K3: x0 = relu(high @ W0 + b0), 128x128 tiles
  gemm128_kernel<<<dim3(4, 128), 256, 0, stream>>>(high, w0T, b0, x0, 256, 512);
  // K4: x1 GEMM + W2 + softmax + target
  gemm_w1_final_kernel<<<256, 256, 0, stream>>>(x0, w1T, b1, w2T, b2, target, out);
}